// Round 2
// 1529.724 us; speedup vs baseline: 1.0631x; 1.0631x over previous
//
#include <hip/hip_runtime.h>
#include <hip/hip_fp16.h>

// ---------------------------------------------------------------------------
// 4-layer GCN.
// degree -> dis=rsqrt(deg+1) -> CSR by dst (two-phase bucketed build) ->
// 4x [MFMA fp16 GEMM (row-prescaled by dis, f32 accum), aggregate(+bias,
// +leaky, fp16 out)] -> softmax fused in last agg.
// H' = dis[row]*(A@W) stored fp16 everywhere.
//
// CSR build: the old single-pass k_fill scattered 4B stores over a 12.8MB
// array -> ~194MB WRITE_SIZE (partial-line evictions), 300us. Replaced by:
//   phase 1: append (src<<7|dstLocal) into 782 dst-buckets (128 nodes each)
//            via per-bucket cursors -> write frontier ~50KB, L2-resident.
//   phase 2: one block per bucket places entries into exact csr slots via
//            LDS cursors -> all writes in a ~16KB single-XCD window.
// ---------------------------------------------------------------------------

#define NEG_SLOPE 0.01f

typedef __attribute__((ext_vector_type(8))) _Float16 f16x8;
typedef __attribute__((ext_vector_type(4))) float f32x4;

__device__ inline f16x8 f16x8_zero() {
    f16x8 v;
#pragma unroll
    for (int q = 0; q < 8; ++q) v[q] = (_Float16)0.f;
    return v;
}

// ------------------------------- setup -------------------------------------
__global__ void k_degree(const int* __restrict__ dst, int* __restrict__ cnt, int E) {
    int i = blockIdx.x * 256 + threadIdx.x;
    if (i < E) atomicAdd(&cnt[dst[i]], 1);
}

__global__ void k_dis(const int* __restrict__ cnt, float* __restrict__ dis, int N) {
    int i = blockIdx.x * 256 + threadIdx.x;
    if (i < N) dis[i] = rsqrtf((float)cnt[i] + 1.0f);
}

__global__ void k_scan1(const int* __restrict__ cnt, int* __restrict__ excl,
                        int* __restrict__ partials, int n) {
    __shared__ int tmp[1024];
    int tid = threadIdx.x;
    int i = blockIdx.x * 1024 + tid;
    int v = (i < n) ? cnt[i] : 0;
    tmp[tid] = v;
    __syncthreads();
    for (int off = 1; off < 1024; off <<= 1) {
        int t = (tid >= off) ? tmp[tid - off] : 0;
        __syncthreads();
        tmp[tid] += t;
        __syncthreads();
    }
    if (i < n) excl[i] = tmp[tid] - v;
    if (tid == 1023) partials[blockIdx.x] = tmp[tid];
}

__global__ void k_scan2(int* __restrict__ partials, int n) {
    __shared__ int tmp[1024];
    int tid = threadIdx.x;
    int v = (tid < n) ? partials[tid] : 0;
    tmp[tid] = v;
    __syncthreads();
    for (int off = 1; off < 1024; off <<= 1) {
        int t = (tid >= off) ? tmp[tid - off] : 0;
        __syncthreads();
        tmp[tid] += t;
        __syncthreads();
    }
    if (tid < n) partials[tid] = tmp[tid] - v;
}

__global__ void k_scan3(int* __restrict__ row_ptr, const int* __restrict__ partials,
                        int n, int E) {
    int i = blockIdx.x * 256 + threadIdx.x;
    if (i < n) row_ptr[i] = row_ptr[i] + partials[i >> 10];
    if (i == n) row_ptr[n] = E;
}

// bucket cursors seeded from row_ptr at node multiples of 128.
// cursors padded to 64B stride to avoid same-line atomic ping-pong.
__global__ void k_init_bcur(const int* __restrict__ row_ptr, int* __restrict__ bcur,
                            int nbuk) {
    int b = blockIdx.x * 256 + threadIdx.x;
    if (b < nbuk) bcur[b * 16] = row_ptr[b << 7];
}

// phase 1: bucket-append. entry = (src << 7) | (dst & 127); src < 2^17 fits.
__global__ void k_bucket_fill(const int* __restrict__ src, const int* __restrict__ dst,
                              int* __restrict__ bcur, int* __restrict__ bpool, int E) {
    int i = blockIdx.x * 256 + threadIdx.x;
    if (i < E) {
        int s = src[i], d = dst[i];
        int b = d >> 7;
        int p = atomicAdd(&bcur[b * 16], 1);
        bpool[p] = (s << 7) | (d & 127);
    }
}

// phase 2: exact placement within bucket using LDS cursors.
__global__ __launch_bounds__(256) void k_place(const int* __restrict__ bpool,
                                               const int* __restrict__ row_ptr,
                                               int* __restrict__ csr, int N) {
    __shared__ int cur[128];
    int b = blockIdx.x;
    int n0 = b << 7;
    int nn = min(128, N - n0);
    int tid = threadIdx.x;
    if (tid < nn) cur[tid] = row_ptr[n0 + tid];
    __syncthreads();
    int lo = row_ptr[n0];
    int hi = row_ptr[n0 + nn];
    for (int i = lo + tid; i < hi; i += 256) {
        int e = bpool[i];
        int p = atomicAdd(&cur[e & 127], 1);
        csr[p] = e >> 7;
    }
}

// W[K][Nf] f32 -> Wt[Nf][K] fp16 (tiny matrices, once per call)
__global__ void k_convW(const float* __restrict__ W, _Float16* __restrict__ Wt,
                        int K, int Nf) {
    int gid = blockIdx.x * 256 + threadIdx.x;
    if (gid < K * Nf) {
        int n = gid / K, k = gid - n * K;
        Wt[gid] = (_Float16)W[(size_t)k * Nf + n];
    }
}

// ---------------------------------------------------------------------------
// MFMA fp16 GEMM: C[M,Nf] = rowscale[r] * (A[M,K] @ Wt^T), Wt is [Nf][K] fp16.
// BM=128, BK=32. 256 threads = 4 waves.
//   BN=128: waves 2x2, each 64x64 (4x4 frags of 16x16x32).
//   BN= 64: waves 4x1, each 32x64 (2x4 frags).
// Frag layouts (m89/m91-verified): A[m=lane&15][k=quad*8+j],
// B[n=lane&15][k=quad*8+j], C[col=lane&15, row=quad*4+reg].
// ---------------------------------------------------------------------------
template <int BN, bool A_HALF, bool OUT_HALF>
__global__ __launch_bounds__(256) void k_gemm_mfma(const void* __restrict__ Ap,
                                                   const _Float16* __restrict__ Bt,
                                                   void* __restrict__ Cp,
                                                   const float* __restrict__ rowscale,
                                                   int M, int K, int Nf) {
    constexpr int BM = 128, BK = 32;
    constexpr int WAVES_N = (BN == 128) ? 2 : 1;
    constexpr int WAVES_M = 4 / WAVES_N;
    constexpr int WM = BM / (WAVES_M * 16);   // 4 (BN=128) / 2 (BN=64)
    constexpr int WN = BN / (WAVES_N * 16);   // 4
    constexpr int LDK = BK + 8;               // pad -> 2-way LDS aliasing (free)
    __shared__ _Float16 As[BM][LDK];
    __shared__ _Float16 Bs[BN][LDK];

    const int tid = threadIdx.x;
    const int ln = tid & 63, wv = tid >> 6;
    const int wm = wv / WAVES_N, wn = wv % WAVES_N;
    const int rowq = wm * WM * 16, colq = wn * WN * 16;
    const int rowBase = blockIdx.x * BM;
    const int colBase = blockIdx.y * BN;
    const int l15 = ln & 15, lq = ln >> 4;

    f32x4 acc[WM][WN];
#pragma unroll
    for (int i = 0; i < WM; ++i)
#pragma unroll
        for (int j = 0; j < WN; ++j) {
            acc[i][j][0] = 0.f; acc[i][j][1] = 0.f;
            acc[i][j][2] = 0.f; acc[i][j][3] = 0.f;
        }

    constexpr int ASL2 = (BM * BK / 8) / 256;   // 2
    constexpr int BSL2 = (BN * BK / 8) / 256;   // 2 or 1

    for (int kt = 0; kt < K; kt += BK) {
        // global loads to regs
        f16x8 aL[ASL2];
        float4 aF[ASL2][2];
#pragma unroll
        for (int s2 = 0; s2 < ASL2; ++s2) {
            int s = tid + s2 * 256;
            int r = s >> 2, k0 = (s & 3) * 8;
            int gr = rowBase + r;
            if constexpr (A_HALF) {
                aL[s2] = (gr < M)
                    ? *(const f16x8*)((const _Float16*)Ap + (size_t)gr * K + kt + k0)
                    : f16x8_zero();
            } else {
                if (gr < M) {
                    const float* ap = (const float*)Ap + (size_t)gr * K + kt + k0;
                    aF[s2][0] = *(const float4*)ap;
                    aF[s2][1] = *(const float4*)(ap + 4);
                } else {
                    aF[s2][0] = make_float4(0.f, 0.f, 0.f, 0.f);
                    aF[s2][1] = make_float4(0.f, 0.f, 0.f, 0.f);
                }
            }
        }
        f16x8 bL[BSL2];
#pragma unroll
        for (int s2 = 0; s2 < BSL2; ++s2) {
            int s = tid + s2 * 256;
            int n = s >> 2, k0 = (s & 3) * 8;
            bL[s2] = *(const f16x8*)&Bt[(size_t)(colBase + n) * K + kt + k0];
        }
        __syncthreads();   // previous iteration's frag reads done
        // LDS writes
#pragma unroll
        for (int s2 = 0; s2 < ASL2; ++s2) {
            int s = tid + s2 * 256;
            int r = s >> 2, k0 = (s & 3) * 8;
            if constexpr (A_HALF) {
                *(f16x8*)&As[r][k0] = aL[s2];
            } else {
                f16x8 h;
                h[0] = (_Float16)aF[s2][0].x; h[1] = (_Float16)aF[s2][0].y;
                h[2] = (_Float16)aF[s2][0].z; h[3] = (_Float16)aF[s2][0].w;
                h[4] = (_Float16)aF[s2][1].x; h[5] = (_Float16)aF[s2][1].y;
                h[6] = (_Float16)aF[s2][1].z; h[7] = (_Float16)aF[s2][1].w;
                *(f16x8*)&As[r][k0] = h;
            }
        }
#pragma unroll
        for (int s2 = 0; s2 < BSL2; ++s2) {
            int s = tid + s2 * 256;
            int n = s >> 2, k0 = (s & 3) * 8;
            *(f16x8*)&Bs[n][k0] = bL[s2];
        }
        __syncthreads();
        // frags + MFMA
        f16x8 af[WM], bf[WN];
#pragma unroll
        for (int i = 0; i < WM; ++i)
            af[i] = *(const f16x8*)&As[rowq + i * 16 + l15][lq * 8];
#pragma unroll
        for (int j = 0; j < WN; ++j)
            bf[j] = *(const f16x8*)&Bs[colq + j * 16 + l15][lq * 8];
#pragma unroll
        for (int i = 0; i < WM; ++i)
#pragma unroll
            for (int j = 0; j < WN; ++j)
                acc[i][j] = __builtin_amdgcn_mfma_f32_16x16x32_f16(af[i], bf[j],
                                                                   acc[i][j], 0, 0, 0);
    }

    // epilogue: C[col=l15, row=lq*4+r] per frag; apply rowscale
#pragma unroll
    for (int i = 0; i < WM; ++i) {
#pragma unroll
        for (int r = 0; r < 4; ++r) {
            int row = rowBase + rowq + i * 16 + lq * 4 + r;
            if (row < M) {
                float rs = rowscale[row];
#pragma unroll
                for (int j = 0; j < WN; ++j) {
                    int col = colBase + colq + j * 16 + l15;
                    float v = rs * acc[i][j][r];
                    if constexpr (OUT_HALF)
                        ((_Float16*)Cp)[(size_t)row * Nf + col] = (_Float16)v;
                    else
                        ((float*)Cp)[(size_t)row * Nf + col] = v;
                }
            }
        }
    }
}

// ---------------------------------------------------------------------------
// Aggregate F=256 from fp16 H' (row = 512B; lane reads 8B). f32 accumulate;
// 8 edges batched. out (fp16) = leaky( dis_i*(sum H'[src] + H'[i]) + b )
// ---------------------------------------------------------------------------
__global__ __launch_bounds__(256) void k_agg256_h(const float2* __restrict__ H2,
                                                  const int* __restrict__ row_ptr,
                                                  const int* __restrict__ csr,
                                                  const float* __restrict__ dis,
                                                  const float* __restrict__ bias,
                                                  _Float16* __restrict__ out, int N) {
    int wave = threadIdx.x >> 6;
    int lane = threadIdx.x & 63;
    int node = blockIdx.x * 4 + wave;
    if (node >= N) return;
    int beg = row_ptr[node], end = row_ptr[node + 1];
    float ax = 0.f, ay = 0.f, az = 0.f, aw = 0.f;

    int e = beg;
    for (; e + 8 <= end; e += 8) {
        int msrc = csr[e + (lane & 7)];
#pragma unroll
        for (int j = 0; j < 8; ++j) {
            int s = __shfl(msrc, j);
            float2 raw = H2[(size_t)s * 64 + lane];
            float2 f0 = __half22float2(*(const __half2*)&raw.x);
            float2 f1 = __half22float2(*(const __half2*)&raw.y);
            ax += f0.x; ay += f0.y; az += f1.x; aw += f1.y;
        }
    }
    if (e < end) {
        int idx = e + (lane & 7);
        int msrc = csr[idx < end ? idx : end - 1];
        int n = end - e;
#pragma unroll
        for (int j = 0; j < 8; ++j) {
            if (j < n) {
                int s = __shfl(msrc, j);
                float2 raw = H2[(size_t)s * 64 + lane];
                float2 f0 = __half22float2(*(const __half2*)&raw.x);
                float2 f1 = __half22float2(*(const __half2*)&raw.y);
                ax += f0.x; ay += f0.y; az += f1.x; aw += f1.y;
            }
        }
    }

    float di = dis[node];
    float2 raws = H2[(size_t)node * 64 + lane];
    float2 s0 = __half22float2(*(const __half2*)&raws.x);
    float2 s1 = __half22float2(*(const __half2*)&raws.y);
    float4 b  = ((const float4*)bias)[lane];
    float rx = fmaf(di, ax + s0.x, b.x);
    float ry = fmaf(di, ay + s0.y, b.y);
    float rz = fmaf(di, az + s1.x, b.z);
    float rw = fmaf(di, aw + s1.y, b.w);
    rx = rx > 0.f ? rx : NEG_SLOPE * rx;
    ry = ry > 0.f ? ry : NEG_SLOPE * ry;
    rz = rz > 0.f ? rz : NEG_SLOPE * rz;
    rw = rw > 0.f ? rw : NEG_SLOPE * rw;
    _Float16 hh[4] = {(_Float16)rx, (_Float16)ry, (_Float16)rz, (_Float16)rw};
    *(float2*)&out[(size_t)node * 256 + lane * 4] = *(float2*)hh;
}

// ---------------------------------------------------------------------------
// Aggregate F=64 + softmax from fp16 H' (row = 128B; lane reads 2B).
// ---------------------------------------------------------------------------
__global__ __launch_bounds__(256) void k_agg64_softmax(const _Float16* __restrict__ H,
                                                       const int* __restrict__ row_ptr,
                                                       const int* __restrict__ csr,
                                                       const float* __restrict__ dis,
                                                       const float* __restrict__ bias,
                                                       float* __restrict__ out, int N) {
    int wave = threadIdx.x >> 6;
    int lane = threadIdx.x & 63;
    int node = blockIdx.x * 4 + wave;
    if (node >= N) return;
    int beg = row_ptr[node], end = row_ptr[node + 1];
    float acc = 0.f;

    int e = beg;
    for (; e + 8 <= end; e += 8) {
        int msrc = csr[e + (lane & 7)];
#pragma unroll
        for (int j = 0; j < 8; ++j) {
            int s = __shfl(msrc, j);
            acc += (float)H[(size_t)s * 64 + lane];
        }
    }
    if (e < end) {
        int idx = e + (lane & 7);
        int msrc = csr[idx < end ? idx : end - 1];
        int n = end - e;
#pragma unroll
        for (int j = 0; j < 8; ++j) {
            if (j < n) {
                int s = __shfl(msrc, j);
                acc += (float)H[(size_t)s * 64 + lane];
            }
        }
    }

    float di = dis[node];
    float v = fmaf(di, acc + (float)H[(size_t)node * 64 + lane], bias[lane]);
    float m = v;
#pragma unroll
    for (int off = 32; off; off >>= 1) m = fmaxf(m, __shfl_xor(m, off));
    float ex = __expf(v - m);
    float s = ex;
#pragma unroll
    for (int off = 32; off; off >>= 1) s += __shfl_xor(s, off);
    out[(size_t)node * 64 + lane] = ex / s;
}

// ---------------------------------------------------------------------------
extern "C" void kernel_launch(void* const* d_in, const int* in_sizes, int n_in,
                              void* d_out, int out_size, void* d_ws, size_t ws_size,
                              hipStream_t stream) {
    const float* x  = (const float*)d_in[0];
    const int*   ei = (const int*)d_in[1];
    const float* W0 = (const float*)d_in[2];
    const float* b0 = (const float*)d_in[3];
    const float* W1 = (const float*)d_in[4];
    const float* b1 = (const float*)d_in[5];
    const float* W2 = (const float*)d_in[6];
    const float* b2 = (const float*)d_in[7];
    const float* W3 = (const float*)d_in[8];
    const float* b3 = (const float*)d_in[9];

    const int N = in_sizes[0] / 512;   // 100000
    const int E = in_sizes[1] / 2;     // 3200000
    const int* src = ei;
    const int* dst = ei + E;
    const int NBUK = (N + 127) >> 7;   // 782 buckets of 128 dst nodes

    auto align256 = [](size_t v) { return (v + 255) & ~(size_t)255; };
    char* w = (char*)d_ws;
    _Float16* hA = (_Float16*)w;     w += align256((size_t)N * 256 * 2);  // GEMM out H' (fp16)
    _Float16* hB = (_Float16*)w;     w += align256((size_t)N * 256 * 2);  // agg out (fp16)
    int*   csr = (int*)w;            w += align256((size_t)E * 4);
    int*   bpool = (int*)w;          w += align256((size_t)E * 4);        // bucketed edges
    int*   cnt = (int*)w;            w += align256((size_t)N * 4);
    float* dis = (float*)w;          w += align256((size_t)N * 4);
    int*   row_ptr = (int*)w;        w += align256((size_t)(N + 1) * 4);
    int*   bcur = (int*)w;           w += align256((size_t)NBUK * 16 * 4);
    int*   partials = (int*)w;       w += align256((size_t)1024 * 4);
    _Float16* Wt0 = (_Float16*)w;    w += align256((size_t)256 * 512 * 2);
    _Float16* Wt1 = (_Float16*)w;    w += align256((size_t)256 * 256 * 2);
    _Float16* Wt2 = (_Float16*)w;    w += align256((size_t)256 * 256 * 2);
    _Float16* Wt3 = (_Float16*)w;    w += align256((size_t)64 * 256 * 2);
    (void)ws_size; (void)n_in; (void)out_size;

    const int nchunks = (N + 1023) / 1024;

    hipMemsetAsync(cnt, 0, (size_t)N * 4, stream);
    k_degree<<<(E + 255) / 256, 256, 0, stream>>>(dst, cnt, E);
    k_dis<<<(N + 255) / 256, 256, 0, stream>>>(cnt, dis, N);
    k_scan1<<<nchunks, 1024, 0, stream>>>(cnt, row_ptr, partials, N);
    k_scan2<<<1, 1024, 0, stream>>>(partials, nchunks);
    k_scan3<<<(N + 1 + 255) / 256, 256, 0, stream>>>(row_ptr, partials, N, E);
    k_init_bcur<<<(NBUK + 255) / 256, 256, 0, stream>>>(row_ptr, bcur, NBUK);
    k_bucket_fill<<<(E + 255) / 256, 256, 0, stream>>>(src, dst, bcur, bpool, E);
    k_place<<<NBUK, 256, 0, stream>>>(bpool, row_ptr, csr, N);

    k_convW<<<(512 * 256 + 255) / 256, 256, 0, stream>>>(W0, Wt0, 512, 256);
    k_convW<<<(256 * 256 + 255) / 256, 256, 0, stream>>>(W1, Wt1, 256, 256);
    k_convW<<<(256 * 256 + 255) / 256, 256, 0, stream>>>(W2, Wt2, 256, 256);
    k_convW<<<(256 * 64 + 255) / 256, 256, 0, stream>>>(W3, Wt3, 256, 64);

    const int gridM = (N + 127) / 128;
    const int nodeBlocks = (N + 3) / 4;

    // layer 0: x(f32) @ Wt0 -> hA fp16 ; agg -> hB fp16
    k_gemm_mfma<128, false, true><<<dim3(gridM, 2), 256, 0, stream>>>(x, Wt0, hA, dis,
                                                                      N, 512, 256);
    k_agg256_h<<<nodeBlocks, 256, 0, stream>>>((const float2*)hA, row_ptr, csr, dis, b0,
                                               hB, N);
    // layer 1
    k_gemm_mfma<128, true, true><<<dim3(gridM, 2), 256, 0, stream>>>(hB, Wt1, hA, dis,
                                                                     N, 256, 256);
    k_agg256_h<<<nodeBlocks, 256, 0, stream>>>((const float2*)hA, row_ptr, csr, dis, b1,
                                               hB, N);
    // layer 2
    k_gemm_mfma<128, true, true><<<dim3(gridM, 2), 256, 0, stream>>>(hB, Wt2, hA, dis,
                                                                     N, 256, 256);
    k_agg256_h<<<nodeBlocks, 256, 0, stream>>>((const float2*)hA, row_ptr, csr, dis, b2,
                                               hB, N);
    // layer 3: hB fp16 @ Wt3 -> hA fp16 (N x 64) ; agg + softmax -> d_out (f32)
    k_gemm_mfma<64, true, true><<<dim3(gridM, 1), 256, 0, stream>>>(hB, Wt3, hA, dis,
                                                                    N, 256, 64);
    k_agg64_softmax<<<nodeBlocks, 256, 0, stream>>>(hA, row_ptr, csr, dis, b3,
                                                    (float*)d_out, N);
}

// Round 5
// 1493.432 us; speedup vs baseline: 1.0889x; 1.0243x over previous
//
#include <hip/hip_runtime.h>
#include <hip/hip_fp16.h>

// ---------------------------------------------------------------------------
// 4-layer GCN.
// degree -> dis=rsqrt(deg+1) -> CSR by dst (two-phase bucketed build) ->
// 4x [MFMA fp16 GEMM (row-prescaled by dis, f32 accum), aggregate(+bias,
// +leaky, fp16 out)] -> softmax fused in last agg.
// H' = dis[row]*(A@W) stored fp16 everywhere.
//
// Aggregation kernels use wide gathers:
//   agg256: 16B/lane, 32 lanes/row -> 2 edges per load instr (1KB), 16-edge
//           batches; cross-half combine via shfl_xor(32).
//   agg64:  16B/lane, 8 lanes/row -> 8 edges per load instr (1KB), 32-edge
//           batches; combine via shfl_xor(8,16,32).
// ---------------------------------------------------------------------------

#define NEG_SLOPE 0.01f

typedef __attribute__((ext_vector_type(8))) _Float16 f16x8;
typedef __attribute__((ext_vector_type(4))) float f32x4;

__device__ inline f16x8 f16x8_zero() {
    f16x8 v;
#pragma unroll
    for (int q = 0; q < 8; ++q) v[q] = (_Float16)0.f;
    return v;
}

// ------------------------------- setup -------------------------------------
__global__ void k_degree(const int* __restrict__ dst, int* __restrict__ cnt, int E) {
    int i = blockIdx.x * 256 + threadIdx.x;
    if (i < E) atomicAdd(&cnt[dst[i]], 1);
}

__global__ void k_dis(const int* __restrict__ cnt, float* __restrict__ dis, int N) {
    int i = blockIdx.x * 256 + threadIdx.x;
    if (i < N) dis[i] = rsqrtf((float)cnt[i] + 1.0f);
}

__global__ void k_scan1(const int* __restrict__ cnt, int* __restrict__ excl,
                        int* __restrict__ partials, int n) {
    __shared__ int tmp[1024];
    int tid = threadIdx.x;
    int i = blockIdx.x * 1024 + tid;
    int v = (i < n) ? cnt[i] : 0;
    tmp[tid] = v;
    __syncthreads();
    for (int off = 1; off < 1024; off <<= 1) {
        int t = (tid >= off) ? tmp[tid - off] : 0;
        __syncthreads();
        tmp[tid] += t;
        __syncthreads();
    }
    if (i < n) excl[i] = tmp[tid] - v;
    if (tid == 1023) partials[blockIdx.x] = tmp[tid];
}

__global__ void k_scan2(int* __restrict__ partials, int n) {
    __shared__ int tmp[1024];
    int tid = threadIdx.x;
    int v = (tid < n) ? partials[tid] : 0;
    tmp[tid] = v;
    __syncthreads();
    for (int off = 1; off < 1024; off <<= 1) {
        int t = (tid >= off) ? tmp[tid - off] : 0;
        __syncthreads();
        tmp[tid] += t;
        __syncthreads();
    }
    if (tid < n) partials[tid] = tmp[tid] - v;
}

__global__ void k_scan3(int* __restrict__ row_ptr, const int* __restrict__ partials,
                        int n, int E) {
    int i = blockIdx.x * 256 + threadIdx.x;
    if (i < n) row_ptr[i] = row_ptr[i] + partials[i >> 10];
    if (i == n) row_ptr[n] = E;
}

// bucket cursors seeded from row_ptr at node multiples of 128.
// cursors padded to 64B stride to avoid same-line atomic ping-pong.
__global__ void k_init_bcur(const int* __restrict__ row_ptr, int* __restrict__ bcur,
                            int nbuk) {
    int b = blockIdx.x * 256 + threadIdx.x;
    if (b < nbuk) bcur[b * 16] = row_ptr[b << 7];
}

// phase 1: bucket-append. entry = (src << 7) | (dst & 127); src < 2^17 fits.
__global__ void k_bucket_fill(const int* __restrict__ src, const int* __restrict__ dst,
                              int* __restrict__ bcur, int* __restrict__ bpool, int E) {
    int i = blockIdx.x * 256 + threadIdx.x;
    if (i < E) {
        int s = src[i], d = dst[i];
        int b = d >> 7;
        int p = atomicAdd(&bcur[b * 16], 1);
        bpool[p] = (s << 7) | (d & 127);
    }
}

// phase 2: exact placement within bucket using LDS cursors.
__global__ __launch_bounds__(256) void k_place(const int* __restrict__ bpool,
                                               const int* __restrict__ row_ptr,
                                               int* __restrict__ csr, int N) {
    __shared__ int cur[128];
    int b = blockIdx.x;
    int n0 = b << 7;
    int nn = min(128, N - n0);
    int tid = threadIdx.x;
    if (tid < nn) cur[tid] = row_ptr[n0 + tid];
    __syncthreads();
    int lo = row_ptr[n0];
    int hi = row_ptr[n0 + nn];
    for (int i = lo + tid; i < hi; i += 256) {
        int e = bpool[i];
        int p = atomicAdd(&cur[e & 127], 1);
        csr[p] = e >> 7;
    }
}

// W[K][Nf] f32 -> Wt[Nf][K] fp16 (tiny matrices, once per call)
__global__ void k_convW(const float* __restrict__ W, _Float16* __restrict__ Wt,
                        int K, int Nf) {
    int gid = blockIdx.x * 256 + threadIdx.x;
    if (gid < K * Nf) {
        int n = gid / K, k = gid - n * K;
        Wt[gid] = (_Float16)W[(size_t)k * Nf + n];
    }
}

// ---------------------------------------------------------------------------
// MFMA fp16 GEMM: C[M,Nf] = rowscale[r] * (A[M,K] @ Wt^T), Wt is [Nf][K] fp16.
// BM=128, BK=32. 256 threads = 4 waves.
//   BN=128: waves 2x2, each 64x64 (4x4 frags of 16x16x32).
//   BN= 64: waves 4x1, each 32x64 (2x4 frags).
// Frag layouts (m89/m91-verified): A[m=lane&15][k=quad*8+j],
// B[n=lane&15][k=quad*8+j], C[col=lane&15, row=quad*4+reg].
// ---------------------------------------------------------------------------
template <int BN, bool A_HALF, bool OUT_HALF>
__global__ __launch_bounds__(256) void k_gemm_mfma(const void* __restrict__ Ap,
                                                   const _Float16* __restrict__ Bt,
                                                   void* __restrict__ Cp,
                                                   const float* __restrict__ rowscale,
                                                   int M, int K, int Nf) {
    constexpr int BM = 128, BK = 32;
    constexpr int WAVES_N = (BN == 128) ? 2 : 1;
    constexpr int WAVES_M = 4 / WAVES_N;
    constexpr int WM = BM / (WAVES_M * 16);   // 4 (BN=128) / 2 (BN=64)
    constexpr int WN = BN / (WAVES_N * 16);   // 4
    constexpr int LDK = BK + 8;               // pad -> 2-way LDS aliasing (free)
    __shared__ _Float16 As[BM][LDK];
    __shared__ _Float16 Bs[BN][LDK];

    const int tid = threadIdx.x;
    const int ln = tid & 63, wv = tid >> 6;
    const int wm = wv / WAVES_N, wn = wv % WAVES_N;
    const int rowq = wm * WM * 16, colq = wn * WN * 16;
    const int rowBase = blockIdx.x * BM;
    const int colBase = blockIdx.y * BN;
    const int l15 = ln & 15, lq = ln >> 4;

    f32x4 acc[WM][WN];
#pragma unroll
    for (int i = 0; i < WM; ++i)
#pragma unroll
        for (int j = 0; j < WN; ++j) {
            acc[i][j][0] = 0.f; acc[i][j][1] = 0.f;
            acc[i][j][2] = 0.f; acc[i][j][3] = 0.f;
        }

    constexpr int ASL2 = (BM * BK / 8) / 256;   // 2
    constexpr int BSL2 = (BN * BK / 8) / 256;   // 2 or 1

    for (int kt = 0; kt < K; kt += BK) {
        // global loads to regs
        f16x8 aL[ASL2];
        float4 aF[ASL2][2];
#pragma unroll
        for (int s2 = 0; s2 < ASL2; ++s2) {
            int s = tid + s2 * 256;
            int r = s >> 2, k0 = (s & 3) * 8;
            int gr = rowBase + r;
            if constexpr (A_HALF) {
                aL[s2] = (gr < M)
                    ? *(const f16x8*)((const _Float16*)Ap + (size_t)gr * K + kt + k0)
                    : f16x8_zero();
            } else {
                if (gr < M) {
                    const float* ap = (const float*)Ap + (size_t)gr * K + kt + k0;
                    aF[s2][0] = *(const float4*)ap;
                    aF[s2][1] = *(const float4*)(ap + 4);
                } else {
                    aF[s2][0] = make_float4(0.f, 0.f, 0.f, 0.f);
                    aF[s2][1] = make_float4(0.f, 0.f, 0.f, 0.f);
                }
            }
        }
        f16x8 bL[BSL2];
#pragma unroll
        for (int s2 = 0; s2 < BSL2; ++s2) {
            int s = tid + s2 * 256;
            int n = s >> 2, k0 = (s & 3) * 8;
            bL[s2] = *(const f16x8*)&Bt[(size_t)(colBase + n) * K + kt + k0];
        }
        __syncthreads();   // previous iteration's frag reads done
        // LDS writes
#pragma unroll
        for (int s2 = 0; s2 < ASL2; ++s2) {
            int s = tid + s2 * 256;
            int r = s >> 2, k0 = (s & 3) * 8;
            if constexpr (A_HALF) {
                *(f16x8*)&As[r][k0] = aL[s2];
            } else {
                f16x8 h;
                h[0] = (_Float16)aF[s2][0].x; h[1] = (_Float16)aF[s2][0].y;
                h[2] = (_Float16)aF[s2][0].z; h[3] = (_Float16)aF[s2][0].w;
                h[4] = (_Float16)aF[s2][1].x; h[5] = (_Float16)aF[s2][1].y;
                h[6] = (_Float16)aF[s2][1].z; h[7] = (_Float16)aF[s2][1].w;
                *(f16x8*)&As[r][k0] = h;
            }
        }
#pragma unroll
        for (int s2 = 0; s2 < BSL2; ++s2) {
            int s = tid + s2 * 256;
            int n = s >> 2, k0 = (s & 3) * 8;
            *(f16x8*)&Bs[n][k0] = bL[s2];
        }
        __syncthreads();
        // frags + MFMA
        f16x8 af[WM], bf[WN];
#pragma unroll
        for (int i = 0; i < WM; ++i)
            af[i] = *(const f16x8*)&As[rowq + i * 16 + l15][lq * 8];
#pragma unroll
        for (int j = 0; j < WN; ++j)
            bf[j] = *(const f16x8*)&Bs[colq + j * 16 + l15][lq * 8];
#pragma unroll
        for (int i = 0; i < WM; ++i)
#pragma unroll
            for (int j = 0; j < WN; ++j)
                acc[i][j] = __builtin_amdgcn_mfma_f32_16x16x32_f16(af[i], bf[j],
                                                                   acc[i][j], 0, 0, 0);
    }

    // epilogue: C[col=l15, row=lq*4+r] per frag; apply rowscale
#pragma unroll
    for (int i = 0; i < WM; ++i) {
#pragma unroll
        for (int r = 0; r < 4; ++r) {
            int row = rowBase + rowq + i * 16 + lq * 4 + r;
            if (row < M) {
                float rs = rowscale[row];
#pragma unroll
                for (int j = 0; j < WN; ++j) {
                    int col = colBase + colq + j * 16 + l15;
                    float v = rs * acc[i][j][r];
                    if constexpr (OUT_HALF)
                        ((_Float16*)Cp)[(size_t)row * Nf + col] = (_Float16)v;
                    else
                        ((float*)Cp)[(size_t)row * Nf + col] = v;
                }
            }
        }
    }
}

// ---------------------------------------------------------------------------
// Aggregate F=256 from fp16 H'. Lane reads 16B (f16x8); 32 lanes cover a
// 512B row; the two wave-halves process different edges -> 2 edges (1KB)
// per load instruction, 16 edges per batch (8 loads in flight per lane).
// out (fp16) = leaky( dis_i*(sum H'[src] + H'[i]) + b )
// ---------------------------------------------------------------------------
__global__ __launch_bounds__(256) void k_agg256_h(const _Float16* __restrict__ H,
                                                  const int* __restrict__ row_ptr,
                                                  const int* __restrict__ csr,
                                                  const float* __restrict__ dis,
                                                  const float* __restrict__ bias,
                                                  _Float16* __restrict__ out, int N) {
    int wave = threadIdx.x >> 6;
    int lane = threadIdx.x & 63;
    int node = blockIdx.x * 4 + wave;
    if (node >= N) return;
    int beg = row_ptr[node], end = row_ptr[node + 1];
    const int half = lane >> 5;           // 0/1: which edge of each pair
    const int fo = (lane & 31) * 8;       // feature chunk [fo, fo+8)

    float acc[8];
#pragma unroll
    for (int q = 0; q < 8; ++q) acc[q] = 0.f;

    int e = beg;
    for (; e + 16 <= end; e += 16) {
        int msrc = csr[e + (lane & 15)];
#pragma unroll
        for (int j = 0; j < 8; ++j) {
            int s = __shfl(msrc, 2 * j + half);
            f16x8 v = *(const f16x8*)(H + (size_t)s * 256 + fo);
#pragma unroll
            for (int q = 0; q < 8; ++q) acc[q] += (float)v[q];
        }
    }
    if (e < end) {
        int n = end - e;
        int idx = e + (lane & 15);
        int msrc = csr[idx < end ? idx : end - 1];
#pragma unroll
        for (int j = 0; j < 8; ++j) {
            int eidx = 2 * j + half;
            if (eidx < n) {
                int s = __shfl(msrc, eidx);
                f16x8 v = *(const f16x8*)(H + (size_t)s * 256 + fo);
#pragma unroll
                for (int q = 0; q < 8; ++q) acc[q] += (float)v[q];
            }
        }
    }

    // combine the two halves (lane L and L^32 hold same feature chunk)
#pragma unroll
    for (int q = 0; q < 8; ++q) acc[q] += __shfl_xor(acc[q], 32);

    float di = dis[node];
    f16x8 sv = *(const f16x8*)(H + (size_t)node * 256 + fo);
    float4 b0 = ((const float4*)bias)[(lane & 31) * 2];
    float4 b1 = ((const float4*)bias)[(lane & 31) * 2 + 1];
    float bb[8] = {b0.x, b0.y, b0.z, b0.w, b1.x, b1.y, b1.z, b1.w};
    f16x8 hh;
#pragma unroll
    for (int q = 0; q < 8; ++q) {
        float r = fmaf(di, acc[q] + (float)sv[q], bb[q]);
        r = r > 0.f ? r : NEG_SLOPE * r;
        hh[q] = (_Float16)r;
    }
    if (half == 0)
        *(f16x8*)(out + (size_t)node * 256 + fo) = hh;
}

// ---------------------------------------------------------------------------
// Aggregate F=64 + softmax from fp16 H'. Lane reads 16B; 8 lanes cover a
// 128B row; 8 lane-groups process different edges -> 8 edges (1KB) per load
// instruction, 32 edges per batch. Combine via shfl_xor(8,16,32).
// ---------------------------------------------------------------------------
__global__ __launch_bounds__(256) void k_agg64_softmax(const _Float16* __restrict__ H,
                                                       const int* __restrict__ row_ptr,
                                                       const int* __restrict__ csr,
                                                       const float* __restrict__ dis,
                                                       const float* __restrict__ bias,
                                                       float* __restrict__ out, int N) {
    int wave = threadIdx.x >> 6;
    int lane = threadIdx.x & 63;
    int node = blockIdx.x * 4 + wave;
    if (node >= N) return;
    int beg = row_ptr[node], end = row_ptr[node + 1];
    const int g = lane >> 3;              // edge group 0..7
    const int fo = (lane & 7) * 8;        // feature chunk [fo, fo+8)

    float acc[8];
#pragma unroll
    for (int q = 0; q < 8; ++q) acc[q] = 0.f;

    int e = beg;
    for (; e + 32 <= end; e += 32) {
        int msrc = csr[e + (lane & 31)];
#pragma unroll
        for (int j = 0; j < 4; ++j) {
            int s = __shfl(msrc, 8 * j + g);
            f16x8 v = *(const f16x8*)(H + (size_t)s * 64 + fo);
#pragma unroll
            for (int q = 0; q < 8; ++q) acc[q] += (float)v[q];
        }
    }
    if (e < end) {
        int n = end - e;
        int idx = e + (lane & 31);
        int msrc = csr[idx < end ? idx : end - 1];
#pragma unroll
        for (int j = 0; j < 4; ++j) {
            int eidx = 8 * j + g;
            if (eidx < n) {
                int s = __shfl(msrc, eidx);
                f16x8 v = *(const f16x8*)(H + (size_t)s * 64 + fo);
#pragma unroll
                for (int q = 0; q < 8; ++q) acc[q] += (float)v[q];
            }
        }
    }

    // combine 8 edge-groups: all lanes with equal (lane&7) end identical
#pragma unroll
    for (int q = 0; q < 8; ++q) {
        acc[q] += __shfl_xor(acc[q], 8);
        acc[q] += __shfl_xor(acc[q], 16);
        acc[q] += __shfl_xor(acc[q], 32);
    }

    float di = dis[node];
    f16x8 sv = *(const f16x8*)(H + (size_t)node * 64 + fo);
    float4 b0 = ((const float4*)bias)[(lane & 7) * 2];
    float4 b1 = ((const float4*)bias)[(lane & 7) * 2 + 1];
    float bb[8] = {b0.x, b0.y, b0.z, b0.w, b1.x, b1.y, b1.z, b1.w};
    float v[8];
    float m = -3.4e38f;
#pragma unroll
    for (int q = 0; q < 8; ++q) {
        v[q] = fmaf(di, acc[q] + (float)sv[q], bb[q]);
        m = fmaxf(m, v[q]);
    }
#pragma unroll
    for (int off = 4; off; off >>= 1) m = fmaxf(m, __shfl_xor(m, off));
    float s = 0.f;
    float ex[8];
#pragma unroll
    for (int q = 0; q < 8; ++q) { ex[q] = __expf(v[q] - m); s += ex[q]; }
#pragma unroll
    for (int off = 4; off; off >>= 1) s += __shfl_xor(s, off);
    float inv = 1.f / s;
    if (g == 0) {
        float4 o0 = make_float4(ex[0] * inv, ex[1] * inv, ex[2] * inv, ex[3] * inv);
        float4 o1 = make_float4(ex[4] * inv, ex[5] * inv, ex[6] * inv, ex[7] * inv);
        float* op = out + (size_t)node * 64 + fo;
        *(float4*)op = o0;
        *(float4*)(op + 4) = o1;
    }
}

// ---------------------------------------------------------------------------
extern "C" void kernel_launch(void* const* d_in, const int* in_sizes, int n_in,
                              void* d_out, int out_size, void* d_ws, size_t ws_size,
                              hipStream_t stream) {
    const float* x  = (const float*)d_in[0];
    const int*   ei = (const int*)d_in[1];
    const float* W0 = (const float*)d_in[2];
    const float* b0 = (const float*)d_in[3];
    const float* W1 = (const float*)d_in[4];
    const float* b1 = (const float*)d_in[5];
    const float* W2 = (const float*)d_in[6];
    const float* b2 = (const float*)d_in[7];
    const float* W3 = (const float*)d_in[8];
    const float* b3 = (const float*)d_in[9];

    const int N = in_sizes[0] / 512;   // 100000
    const int E = in_sizes[1] / 2;     // 3200000
    const int* src = ei;
    const int* dst = ei + E;
    const int NBUK = (N + 127) >> 7;   // buckets of 128 dst nodes

    auto align256 = [](size_t v) { return (v + 255) & ~(size_t)255; };
    char* w = (char*)d_ws;
    _Float16* hA = (_Float16*)w;     w += align256((size_t)N * 256 * 2);  // GEMM out H' (fp16)
    _Float16* hB = (_Float16*)w;     w += align256((size_t)N * 256 * 2);  // agg out (fp16)
    int*   csr = (int*)w;            w += align256((size_t)E * 4);
    int*   bpool = (int*)w;          w += align256((size_t)E * 4);        // bucketed edges
    int*   cnt = (int*)w;            w += align256((size_t)N * 4);
    float* dis = (float*)w;          w += align256((size_t)N * 4);
    int*   row_ptr = (int*)w;        w += align256((size_t)(N + 1) * 4);
    int*   bcur = (int*)w;           w += align256((size_t)NBUK * 16 * 4);
    int*   partials = (int*)w;       w += align256((size_t)1024 * 4);
    _Float16* Wt0 = (_Float16*)w;    w += align256((size_t)256 * 512 * 2);
    _Float16* Wt1 = (_Float16*)w;    w += align256((size_t)256 * 256 * 2);
    _Float16* Wt2 = (_Float16*)w;    w += align256((size_t)256 * 256 * 2);
    _Float16* Wt3 = (_Float16*)w;    w += align256((size_t)64 * 256 * 2);
    (void)ws_size; (void)n_in; (void)out_size;

    const int nchunks = (N + 1023) / 1024;

    hipMemsetAsync(cnt, 0, (size_t)N * 4, stream);
    k_degree<<<(E + 255) / 256, 256, 0, stream>>>(dst, cnt, E);
    k_dis<<<(N + 255) / 256, 256, 0, stream>>>(cnt, dis, N);
    k_scan1<<<nchunks, 1024, 0, stream>>>(cnt, row_ptr, partials, N);
    k_scan2<<<1, 1024, 0, stream>>>(partials, nchunks);
    k_scan3<<<(N + 1 + 255) / 256, 256, 0, stream>>>(row_ptr, partials, N, E);
    k_init_bcur<<<(NBUK + 255) / 256, 256, 0, stream>>>(row_ptr, bcur, NBUK);
    k_bucket_fill<<<(E + 255) / 256, 256, 0, stream>>>(src, dst, bcur, bpool, E);
    k_place<<<NBUK, 256, 0, stream>>>(bpool, row_ptr, csr, N);

    k_convW<<<(512 * 256 + 255) / 256, 256, 0, stream>>>(W0, Wt0, 512, 256);
    k_convW<<<(256 * 256 + 255) / 256, 256, 0, stream>>>(W1, Wt1, 256, 256);
    k_convW<<<(256 * 256 + 255) / 256, 256, 0, stream>>>(W2, Wt2, 256, 256);
    k_convW<<<(256 * 64 + 255) / 256, 256, 0, stream>>>(W3, Wt3, 256, 64);

    const int gridM = (N + 127) / 128;
    const int nodeBlocks = (N + 3) / 4;

    // layer 0: x(f32) @ Wt0 -> hA fp16 ; agg -> hB fp16
    k_gemm_mfma<128, false, true><<<dim3(gridM, 2), 256, 0, stream>>>(x, Wt0, hA, dis,
                                                                      N, 512, 256);
    k_agg256_h<<<nodeBlocks, 256, 0, stream>>>(hA, row_ptr, csr, dis, b0, hB, N);
    // layer 1
    k_gemm_mfma<128, true, true><<<dim3(gridM, 2), 256, 0, stream>>>(hB, Wt1, hA, dis,
                                                                     N, 256, 256);
    k_agg256_h<<<nodeBlocks, 256, 0, stream>>>(hA, row_ptr, csr, dis, b1, hB, N);
    // layer 2
    k_gemm_mfma<128, true, true><<<dim3(gridM, 2), 256, 0, stream>>>(hB, Wt2, hA, dis,
                                                                     N, 256, 256);
    k_agg256_h<<<nodeBlocks, 256, 0, stream>>>(hA, row_ptr, csr, dis, b2, hB, N);
    // layer 3: hB fp16 @ Wt3 -> hA fp16 (N x 64) ; agg + softmax -> d_out (f32)
    k_gemm_mfma<64, true, true><<<dim3(gridM, 1), 256, 0, stream>>>(hB, Wt3, hA, dis,
                                                                    N, 256, 64);
    k_agg64_softmax<<<nodeBlocks, 256, 0, stream>>>(hA, row_ptr, csr, dis, b3,
                                                    (float*)d_out, N);
}